// Round 17
// baseline (636.254 us; speedup 1.0000x reference)
//
#include <hip/hip_runtime.h>
#include <math.h>

#define BB 8
#define NN 1024
#define KNN 20

typedef unsigned short u16;
typedef __bf16 bf16x8 __attribute__((ext_vector_type(8)));
typedef float floatx4 __attribute__((ext_vector_type(4)));

__device__ __forceinline__ float gelu_erf(float x) {
    return 0.5f * x * (1.0f + erff(x * 0.70710678118654752440f));
}

__device__ __forceinline__ u16 f2bf(float f) {
    unsigned int u = __float_as_uint(f);
    unsigned int r = (u + 0x7fffu + ((u >> 16) & 1u)) >> 16;
    return (u16)r;
}
__device__ __forceinline__ float bf2f(u16 h) {
    return __uint_as_float(((unsigned int)h) << 16);
}

// stats layout: 4 edge blocks x (s1[16][O] | s2[16][O]) + blk5 (s1[8][1024] | s2[8][1024])
#define STATS_BLK 32768
#define STATS_TOTAL (4 * STATS_BLK + 16384)
#define ZERO_TOTAL (STATS_TOTAL + 3 * 8192)

// ---- transpose x (B,C,N) -> x0 (B,N,3); zero stat + sq regions ----
__global__ void k_transpose(const float* __restrict__ x, float* __restrict__ x0,
                            float* __restrict__ sz) {
    int t = blockIdx.x * 256 + threadIdx.x;
    for (int i = t; i < ZERO_TOTAL; i += BB * NN) sz[i] = 0.f;
    if (t >= BB * NN) return;
    int b = t / NN, n = t % NN;
    #pragma unroll
    for (int c = 0; c < 3; ++c) x0[(size_t)t * 3 + c] = x[((size_t)b * 3 + c) * NN + n];
}

// ---- one-time weight prep ----
#define SEG2 16384
#define SEG3 81920
#define SEG4 344064
#define SEGT 1327104
__global__ void k_prep_w(const float* __restrict__ W2, const float* __restrict__ W3,
                         const float* __restrict__ W4, const float* __restrict__ W5,
                         u16* __restrict__ wh, u16* __restrict__ wl) {
    int t = blockIdx.x * 256 + threadIdx.x;
    if (t >= SEGT) return;
    float v;
    if (t < SEG2) {
        int row = t >> 6, c = t & 63;
        v = (row < 128) ? W2[row * 128 + c]
                        : W2[(row - 128) * 128 + 64 + c] - W2[(row - 128) * 128 + c];
    } else if (t < SEG3) {
        int i = t - SEG2;
        int row = i >> 7, c = i & 127;
        v = (row < 256) ? W3[row * 256 + c]
                        : W3[(row - 256) * 256 + 128 + c] - W3[(row - 256) * 256 + c];
    } else if (t < SEG4) {
        int i = t - SEG3;
        int row = i >> 8, c = i & 255;
        v = (row < 512) ? W4[row * 512 + c]
                        : W4[(row - 512) * 512 + 256 + c] - W4[(row - 512) * 512 + c];
    } else {
        int i = t - SEG4;
        int row = i / 960, c = i % 960;
        v = W5[row * 960 + c];
    }
    u16 h = f2bf(v);
    wh[t] = h;
    wl[t] = f2bf(v - bf2f(h));
}

// ---- fp32 negd for blk1 (C=3): exact ----
__global__ void k_negd(const float* __restrict__ X, int SA, int Kc, float* __restrict__ out) {
    int bz = blockIdx.z;
    const float* Xb = X + (size_t)bz * NN * SA;
    float* Cout = out + (size_t)bz * NN * NN;
    int m0 = blockIdx.y * 128, n0 = blockIdx.x * 128;
    __shared__ float As[16][132];
    __shared__ float Bs[16][132];
    __shared__ float sqA[128];
    __shared__ float sqB[128];
    int t = threadIdx.x;
    int tx = t & 15, ty = t >> 4;
    int r = t >> 1, kb = (t & 1) * 8;
    float acc[2][2][4][4] = {};
    float sqa = 0.f, sqb = 0.f;
    for (int k0 = 0; k0 < Kc; k0 += 16) {
        const float* srcA = Xb + (size_t)(m0 + r) * SA + k0 + kb;
        const float* srcB = Xb + (size_t)(n0 + r) * SA + k0 + kb;
        #pragma unroll
        for (int i = 0; i < 8; ++i) {
            float va = (k0 + kb + i < Kc) ? srcA[i] : 0.f;
            float vb = (k0 + kb + i < Kc) ? srcB[i] : 0.f;
            As[kb + i][r] = va;
            Bs[kb + i][r] = vb;
            sqa = fmaf(va, va, sqa);
            sqb = fmaf(vb, vb, sqb);
        }
        __syncthreads();
        #pragma unroll
        for (int kk = 0; kk < 16; ++kk) {
            float4 a0 = *(const float4*)&As[kk][ty * 4];
            float4 a1 = *(const float4*)&As[kk][64 + ty * 4];
            float4 b0 = *(const float4*)&Bs[kk][tx * 4];
            float4 b1 = *(const float4*)&Bs[kk][64 + tx * 4];
            float av[2][4] = {{a0.x, a0.y, a0.z, a0.w}, {a1.x, a1.y, a1.z, a1.w}};
            float bv[2][4] = {{b0.x, b0.y, b0.z, b0.w}, {b1.x, b1.y, b1.z, b1.w}};
            #pragma unroll
            for (int hm = 0; hm < 2; ++hm)
                #pragma unroll
                for (int hn = 0; hn < 2; ++hn)
                    #pragma unroll
                    for (int i = 0; i < 4; ++i)
                        #pragma unroll
                        for (int j = 0; j < 4; ++j)
                            acc[hm][hn][i][j] = fmaf(av[hm][i], bv[hn][j], acc[hm][hn][i][j]);
        }
        __syncthreads();
    }
    sqa += __shfl_xor(sqa, 1);
    sqb += __shfl_xor(sqb, 1);
    if ((t & 1) == 0) { sqA[r] = sqa; sqB[r] = sqb; }
    __syncthreads();
    #pragma unroll
    for (int hm = 0; hm < 2; ++hm)
        #pragma unroll
        for (int i = 0; i < 4; ++i) {
            int lrow = hm * 64 + ty * 4 + i;
            float sm = sqA[lrow];
            float* crow = Cout + (size_t)(m0 + lrow) * NN + n0;
            #pragma unroll
            for (int hn = 0; hn < 2; ++hn) {
                float4 sn = *(const float4*)&sqB[hn * 64 + tx * 4];
                float4 v;
                v.x = 2.f * acc[hm][hn][i][0] - sm - sn.x;
                v.y = 2.f * acc[hm][hn][i][1] - sm - sn.y;
                v.z = 2.f * acc[hm][hn][i][2] - sm - sn.z;
                v.w = 2.f * acc[hm][hn][i][3] - sm - sn.w;
                *(float4*)&crow[hn * 64 + tx * 4] = v;
            }
        }
}

// ============ combined GRAM + uw split-bf16 MFMA (blk2-4), one launch ============
// Fragment-major LDS layout [q-octet][row][8].
__global__ __launch_bounds__(256) void k_mfma_comb(
    const u16* __restrict__ Ah, const u16* __restrict__ Al,
    const u16* __restrict__ Wh, const u16* __restrict__ Wl,
    const float* __restrict__ sqg,
    float* __restrict__ negdOut, float* __restrict__ uwOut,
    int K, int ldUw) {
    const int lda = 960;
    int bx = blockIdx.x, by = blockIdx.y;
    bool gram = (by < 8);
    int m0, n0, rowBase;
    const u16 *pBh, *pBl;
    size_t ldb;
    float* pC;
    if (gram) {
        int b = bx & 7;
        n0 = (bx >> 3) * 128;
        m0 = by * 128;
        rowBase = b * NN;
        pBh = Ah; pBl = Al; ldb = lda;
        pC = negdOut + (size_t)b * NN * NN;
    } else {
        m0 = bx * 128;
        n0 = (by - 8) * 128;
        rowBase = 0;
        pBh = Wh; pBl = Wl; ldb = K;
        pC = uwOut;
    }
    __shared__ u16 sAh[4 * 1024];
    __shared__ u16 sAl[4 * 1024];
    __shared__ u16 sBh[4 * 1024];
    __shared__ u16 sBl[4 * 1024];
    __shared__ float sqA[128];
    __shared__ float sqB[128];
    int t = threadIdx.x;
    int w = t >> 6, lane = t & 63;
    int wm = (w & 1) * 64, wn = (w >> 1) * 64;
    int q = lane >> 4, lm = lane & 15;
    int r = t >> 1, cb = (t & 1) * 16;
    int q0 = (t & 1) * 2;
    if (gram) {
        if (t < 128) sqA[t] = sqg[rowBase + m0 + t];
        else if (t < 256) sqB[t - 128] = sqg[rowBase + n0 + (t - 128)];
    }
    floatx4 acc[4][4];
    #pragma unroll
    for (int i = 0; i < 4; ++i)
        #pragma unroll
        for (int j = 0; j < 4; ++j) {
            floatx4 z = {0.f, 0.f, 0.f, 0.f};
            acc[i][j] = z;
        }
    for (int k0 = 0; k0 < K; k0 += 32) {
        {
            size_t oa = (size_t)(rowBase + m0 + r) * lda + k0 + cb;
            size_t ob = gram ? (size_t)(rowBase + n0 + r) * lda + k0 + cb
                             : (size_t)(n0 + r) * ldb + k0 + cb;
            float4 ah0 = *(const float4*)&Ah[oa];
            float4 ah1 = *(const float4*)&Ah[oa + 8];
            float4 al0 = *(const float4*)&Al[oa];
            float4 al1 = *(const float4*)&Al[oa + 8];
            float4 bh0 = *(const float4*)&pBh[ob];
            float4 bh1 = *(const float4*)&pBh[ob + 8];
            float4 bl0 = *(const float4*)&pBl[ob];
            float4 bl1 = *(const float4*)&pBl[ob + 8];
            *(float4*)&sAh[q0 * 1024 + r * 8] = ah0;
            *(float4*)&sAh[(q0 + 1) * 1024 + r * 8] = ah1;
            *(float4*)&sAl[q0 * 1024 + r * 8] = al0;
            *(float4*)&sAl[(q0 + 1) * 1024 + r * 8] = al1;
            *(float4*)&sBh[q0 * 1024 + r * 8] = bh0;
            *(float4*)&sBh[(q0 + 1) * 1024 + r * 8] = bh1;
            *(float4*)&sBl[q0 * 1024 + r * 8] = bl0;
            *(float4*)&sBl[(q0 + 1) * 1024 + r * 8] = bl1;
        }
        __syncthreads();
        bf16x8 ah[4], al[4], bh[4], bl[4];
        #pragma unroll
        for (int i = 0; i < 4; ++i) {
            ah[i] = *(const bf16x8*)&sAh[q * 1024 + (wm + i * 16 + lm) * 8];
            al[i] = *(const bf16x8*)&sAl[q * 1024 + (wm + i * 16 + lm) * 8];
        }
        #pragma unroll
        for (int j = 0; j < 4; ++j) {
            bh[j] = *(const bf16x8*)&sBh[q * 1024 + (wn + j * 16 + lm) * 8];
            bl[j] = *(const bf16x8*)&sBl[q * 1024 + (wn + j * 16 + lm) * 8];
        }
        #pragma unroll
        for (int i = 0; i < 4; ++i)
            #pragma unroll
            for (int j = 0; j < 4; ++j) {
                acc[i][j] = __builtin_amdgcn_mfma_f32_16x16x32_bf16(ah[i], bh[j], acc[i][j], 0, 0, 0);
                acc[i][j] = __builtin_amdgcn_mfma_f32_16x16x32_bf16(ah[i], bl[j], acc[i][j], 0, 0, 0);
                acc[i][j] = __builtin_amdgcn_mfma_f32_16x16x32_bf16(al[i], bh[j], acc[i][j], 0, 0, 0);
            }
        __syncthreads();
    }
    if (gram) {
        #pragma unroll
        for (int i = 0; i < 4; ++i)
            #pragma unroll
            for (int j = 0; j < 4; ++j) {
                int coll = wn + j * 16 + lm;
                float sn = sqB[coll];
                #pragma unroll
                for (int rr = 0; rr < 4; ++rr) {
                    int rowl = wm + i * 16 + q * 4 + rr;
                    pC[(size_t)(m0 + rowl) * NN + n0 + coll] =
                        2.f * acc[i][j][rr] - sqA[rowl] - sn;
                }
            }
    } else {
        #pragma unroll
        for (int i = 0; i < 4; ++i) {
            int rowb = m0 + wm + i * 16 + q * 4;
            #pragma unroll
            for (int j = 0; j < 4; ++j) {
                int col = n0 + wn + j * 16 + lm;
                #pragma unroll
                for (int rr = 0; rr < 4; ++rr)
                    pC[(size_t)(rowb + rr) * ldUw + col] = acc[i][j][rr];
            }
        }
    }
}

// ============ split-bf16 MFMA GEMM (block 5): 128x64 tiles for occupancy ============
// 4 waves 2x2; each wave 64x32 (4x2 frags). B planes padded (stride 520/octet).
__global__ __launch_bounds__(256) void k_mfma16(
    const u16* __restrict__ Ah, const u16* __restrict__ Al, int lda,
    const u16* __restrict__ Bh, const u16* __restrict__ Bl, int ldb,
    float* __restrict__ Cout, int ldc, int K) {
    int m0 = blockIdx.y * 128, n0 = blockIdx.x * 64;
    __shared__ u16 sAh[4 * 1024];
    __shared__ u16 sAl[4 * 1024];
    __shared__ u16 sBh[4 * 520];
    __shared__ u16 sBl[4 * 520];
    int t = threadIdx.x;
    int w = t >> 6, lane = t & 63;
    int wm = (w & 1) * 64, wn = (w >> 1) * 32;
    int q = lane >> 4, lm = lane & 15;
    int r = t >> 1, cb = (t & 1) * 16;
    int q0 = (t & 1) * 2;
    int rB = t >> 2, qB = t & 3;
    floatx4 acc[4][2];
    #pragma unroll
    for (int i = 0; i < 4; ++i)
        #pragma unroll
        for (int j = 0; j < 2; ++j) {
            floatx4 z = {0.f, 0.f, 0.f, 0.f};
            acc[i][j] = z;
        }
    for (int k0 = 0; k0 < K; k0 += 32) {
        {
            size_t oa = (size_t)(m0 + r) * lda + k0 + cb;
            size_t ob = (size_t)(n0 + rB) * ldb + k0 + qB * 8;
            float4 ah0 = *(const float4*)&Ah[oa];
            float4 ah1 = *(const float4*)&Ah[oa + 8];
            float4 al0 = *(const float4*)&Al[oa];
            float4 al1 = *(const float4*)&Al[oa + 8];
            float4 bh0 = *(const float4*)&Bh[ob];
            float4 bl0 = *(const float4*)&Bl[ob];
            *(float4*)&sAh[q0 * 1024 + r * 8] = ah0;
            *(float4*)&sAh[(q0 + 1) * 1024 + r * 8] = ah1;
            *(float4*)&sAl[q0 * 1024 + r * 8] = al0;
            *(float4*)&sAl[(q0 + 1) * 1024 + r * 8] = al1;
            *(float4*)&sBh[qB * 520 + rB * 8] = bh0;
            *(float4*)&sBl[qB * 520 + rB * 8] = bl0;
        }
        __syncthreads();
        bf16x8 ah[4], al[4], bh[2], bl[2];
        #pragma unroll
        for (int i = 0; i < 4; ++i) {
            ah[i] = *(const bf16x8*)&sAh[q * 1024 + (wm + i * 16 + lm) * 8];
            al[i] = *(const bf16x8*)&sAl[q * 1024 + (wm + i * 16 + lm) * 8];
        }
        #pragma unroll
        for (int j = 0; j < 2; ++j) {
            bh[j] = *(const bf16x8*)&sBh[q * 520 + (wn + j * 16 + lm) * 8];
            bl[j] = *(const bf16x8*)&sBl[q * 520 + (wn + j * 16 + lm) * 8];
        }
        #pragma unroll
        for (int i = 0; i < 4; ++i)
            #pragma unroll
            for (int j = 0; j < 2; ++j) {
                acc[i][j] = __builtin_amdgcn_mfma_f32_16x16x32_bf16(ah[i], bh[j], acc[i][j], 0, 0, 0);
                acc[i][j] = __builtin_amdgcn_mfma_f32_16x16x32_bf16(ah[i], bl[j], acc[i][j], 0, 0, 0);
                acc[i][j] = __builtin_amdgcn_mfma_f32_16x16x32_bf16(al[i], bh[j], acc[i][j], 0, 0, 0);
            }
        __syncthreads();
    }
    #pragma unroll
    for (int i = 0; i < 4; ++i) {
        int rowb = m0 + wm + i * 16 + q * 4;
        #pragma unroll
        for (int j = 0; j < 2; ++j) {
            int col = n0 + wn + j * 16 + lm;
            #pragma unroll
            for (int rr = 0; rr < 4; ++rr)
                Cout[(size_t)(rowb + rr) * ldc + col] = acc[i][j][rr];
        }
    }
}

// ---- top-k=20: 2 rows per wave, value-only butterfly + ballot index (R14-proven) ----
__global__ void k_topk(const float* __restrict__ negd, int* __restrict__ idxout) {
    int wv = threadIdx.x >> 6, lane = threadIdx.x & 63;
    int rowA = blockIdx.x * 8 + wv * 2;
    int rowB = rowA + 1;
    const float* dA = negd + (size_t)rowA * NN;
    const float* dB = negd + (size_t)rowB * NN;
    float va[16], vb[16];
    #pragma unroll
    for (int j = 0; j < 16; ++j) {
        va[j] = dA[j * 64 + lane];
        vb[j] = dB[j * 64 + lane];
    }
    float lva = va[0], lvb = vb[0];
    int lca = lane, lcb = lane;
    #pragma unroll
    for (int j = 1; j < 16; ++j) {
        int c = j * 64 + lane;
        if (va[j] > lva) { lva = va[j]; lca = c; }
        if (vb[j] > lvb) { lvb = vb[j]; lcb = c; }
    }
    for (int it = 0; it < KNN; ++it) {
        float ta = lva, tb = lvb;
        #pragma unroll
        for (int s = 32; s >= 1; s >>= 1) {
            float oa = __shfl_xor(ta, s);
            float ob = __shfl_xor(tb, s);
            ta = fmaxf(ta, oa);
            tb = fmaxf(tb, ob);
        }
        unsigned long long ma = __ballot(lva == ta);
        unsigned long long mb = __ballot(lvb == tb);
        int wa = 0x7fffffff, wb = 0x7fffffff;
        while (ma) {
            int l = __ffsll((unsigned long long)ma) - 1;
            int c = __shfl(lca, l);
            wa = min(wa, c);
            ma &= ma - 1;
        }
        while (mb) {
            int l = __ffsll((unsigned long long)mb) - 1;
            int c = __shfl(lcb, l);
            wb = min(wb, c);
            mb &= mb - 1;
        }
        if (lane == 0) {
            idxout[(size_t)rowA * KNN + it] = wa;
            idxout[(size_t)rowB * KNN + it] = wb;
        }
        if ((wa & 63) == lane) {
            int jd = wa >> 6;
            #pragma unroll
            for (int j = 0; j < 16; ++j)
                if (j == jd) va[j] = -INFINITY;
            lva = -INFINITY; lca = 0x7fffffff;
            #pragma unroll
            for (int j = 0; j < 16; ++j) {
                int c = j * 64 + lane;
                if (va[j] > lva) { lva = va[j]; lca = c; }
            }
        }
        if ((wb & 63) == lane) {
            int jd = wb >> 6;
            #pragma unroll
            for (int j = 0; j < 16; ++j)
                if (j == jd) vb[j] = -INFINITY;
            lvb = -INFINITY; lcb = 0x7fffffff;
            #pragma unroll
            for (int j = 0; j < 16; ++j) {
                int c = j * 64 + lane;
                if (vb[j] > lvb) { lvb = vb[j]; lcb = c; }
            }
        }
    }
}

// ---- blk1 uw direct ----
__global__ void k_uw1(const float* __restrict__ x0, const float* __restrict__ W1,
                      float* __restrict__ uw) {
    int t = blockIdx.x * 256 + threadIdx.x;
    if (t >= BB * NN * 128) return;
    int r = t >> 7, o = t & 127;
    float xv0 = x0[(size_t)r * 3], xv1 = x0[(size_t)r * 3 + 1], xv2 = x0[(size_t)r * 3 + 2];
    float acc;
    if (o < 64) {
        const float* wr = W1 + (size_t)o * 6;
        acc = wr[0] * xv0 + wr[1] * xv1 + wr[2] * xv2;
    } else {
        const float* wr = W1 + (size_t)(o - 64) * 6;
        acc = (wr[3] - wr[0]) * xv0 + (wr[4] - wr[1]) * xv1 + (wr[5] - wr[2]) * xv2;
    }
    uw[(size_t)t] = acc;
}

// ---- gather v4: R rows/block, gy channel split, 16-sharded stat atomics ----
__global__ void k_gather4(const float* __restrict__ uw, const int* __restrict__ idx,
                          int O, int ctc, int R,
                          float* __restrict__ hmin, float* __restrict__ hmax,
                          float* __restrict__ s1, float* __restrict__ s2) {
    int t = threadIdx.x;
    int ct = t % ctc, rt = t / ctc;
    int rowsPer = (R * ctc) >> 8;
    int bx = blockIdx.x;
    int b = bx & 7, rg = bx >> 3;
    int row0 = b * NN + rg * R;
    int shard = bx & 15;
    int o4 = blockIdx.y * (ctc * 4) + ct * 4;
    __shared__ int sidx[16 * KNN];
    __shared__ float4 red1[256];
    __shared__ float4 red2[256];
    for (int i = t; i < R * KNN; i += 256) sidx[i] = idx[(size_t)row0 * KNN + i];
    __syncthreads();
    int twoO = 2 * O;
    const float* ubase = uw + (size_t)b * NN * twoO;
    float a1[4] = {0, 0, 0, 0}, a2[4] = {0, 0, 0, 0};
    for (int rr = rt * rowsPer; rr < (rt + 1) * rowsPer; ++rr) {
        int nrow = row0 + rr;
        float4 w4 = *(const float4*)(uw + (size_t)nrow * twoO + O + o4);
        float wv[4] = {w4.x, w4.y, w4.z, w4.w};
        float mn[4], mx[4];
        #pragma unroll
        for (int qq = 0; qq < 4; ++qq) { mn[qq] = INFINITY; mx[qq] = -INFINITY; }
        #pragma unroll 4
        for (int j = 0; j < KNN; ++j) {
            int m = sidx[rr * KNN + j];
            float4 u4 = *(const float4*)(ubase + (size_t)m * twoO + o4);
            float uv[4] = {u4.x, u4.y, u4.z, u4.w};
            #pragma unroll
            for (int qq = 0; qq < 4; ++qq) {
                float h = uv[qq] + wv[qq];
                mn[qq] = fminf(mn[qq], h);
                mx[qq] = fmaxf(mx[qq], h);
                a1[qq] += h;
                a2[qq] = fmaf(h, h, a2[qq]);
            }
        }
        *(float4*)&hmin[(size_t)nrow * O + o4] = make_float4(mn[0], mn[1], mn[2], mn[3]);
        *(float4*)&hmax[(size_t)nrow * O + o4] = make_float4(mx[0], mx[1], mx[2], mx[3]);
    }
    red1[t] = make_float4(a1[0], a1[1], a1[2], a1[3]);
    red2[t] = make_float4(a2[0], a2[1], a2[2], a2[3]);
    __syncthreads();
    if (rt == 0) {
        int rs = 256 / ctc;
        for (int rr = 1; rr < rs; ++rr) {
            float4 v1 = red1[ct + rr * ctc];
            float4 v2 = red2[ct + rr * ctc];
            a1[0] += v1.x; a1[1] += v1.y; a1[2] += v1.z; a1[3] += v1.w;
            a2[0] += v2.x; a2[1] += v2.y; a2[2] += v2.z; a2[3] += v2.w;
        }
        #pragma unroll
        for (int qq = 0; qq < 4; ++qq) {
            atomicAdd(&s1[shard * O + o4 + qq], a1[qq]);
            atomicAdd(&s2[shard * O + o4 + qq], a2[qq]);
        }
    }
}

// ---- BN finalize: reduce 16 shards -> scale/shift ----
__global__ void k_bnfin(const float* __restrict__ s1, const float* __restrict__ s2,
                        const float* __restrict__ g, const float* __restrict__ b,
                        float cnt_inv, int O, float* __restrict__ scale,
                        float* __restrict__ shift) {
    int o = blockIdx.x * 256 + threadIdx.x;
    if (o >= O) return;
    float a1 = 0.f, a2 = 0.f;
    #pragma unroll
    for (int s = 0; s < 16; ++s) {
        a1 += s1[s * O + o];
        a2 += s2[s * O + o];
    }
    float mean = a1 * cnt_inv;
    float var = a2 * cnt_inv - mean * mean;
    float sc = g[o] * rsqrtf(var + 1e-5f);
    scale[o] = sc;
    shift[o] = b[o] - mean * sc;
}

// ---- apply: BN + GELU + maxpool -> bf16 hi/lo planes; optional row-sq ----
__global__ void k_apply(const float* __restrict__ hmin, const float* __restrict__ hmax,
                        const float* __restrict__ scale, const float* __restrict__ shiftv,
                        int O, int shift,
                        u16* __restrict__ outh, u16* __restrict__ outl, int coloff,
                        float* __restrict__ sqout) {
    int gidx = blockIdx.x * 256 + threadIdx.x;
    int row = gidx >> shift;
    int o4 = (gidx & ((1 << shift) - 1)) * 4;
    ushort4 vh, vl;
    float sq = 0.f;
    float vals[4];
    #pragma unroll
    for (int qq = 0; qq < 4; ++qq) {
        int o = o4 + qq;
        float sc = scale[o], sh = shiftv[o];
        float va = gelu_erf(fmaf(sc, hmax[(size_t)row * O + o], sh));
        float vb = gelu_erf(fmaf(sc, hmin[(size_t)row * O + o], sh));
        vals[qq] = fmaxf(va, vb);
        sq = fmaf(vals[qq], vals[qq], sq);
    }
    vh.x = f2bf(vals[0]); vl.x = f2bf(vals[0] - bf2f(vh.x));
    vh.y = f2bf(vals[1]); vl.y = f2bf(vals[1] - bf2f(vh.y));
    vh.z = f2bf(vals[2]); vl.z = f2bf(vals[2] - bf2f(vh.z));
    vh.w = f2bf(vals[3]); vl.w = f2bf(vals[3] - bf2f(vh.w));
    *(ushort4*)&outh[(size_t)row * 960 + coloff + o4] = vh;
    *(ushort4*)&outl[(size_t)row * 960 + coloff + o4] = vl;
    if (sqout) {
        int gsz = 1 << shift;
        if (gsz > 64) gsz = 64;
        #pragma unroll
        for (int s = 1; s < 64; s <<= 1) {
            if (s < gsz) sq += __shfl_xor(sq, s);
        }
        if ((threadIdx.x & (gsz - 1)) == 0) atomicAdd(&sqout[row], sq);
    }
}

// ---- block5: per-column sum/sumsq, 8-sharded ----
__global__ void k_colstats(const float* __restrict__ A, float* __restrict__ s1,
                           float* __restrict__ s2) {
    int o = blockIdx.x * 256 + threadIdx.x;
    int r0 = blockIdx.y * 64;
    int shard = blockIdx.y & 7;
    float a1 = 0.f, a2 = 0.f;
    for (int r = 0; r < 64; ++r) {
        float v = A[(size_t)(r0 + r) * 1024 + o];
        a1 += v;
        a2 = fmaf(v, v, a2);
    }
    atomicAdd(&s1[shard * 1024 + o], a1);
    atomicAdd(&s2[shard * 1024 + o], a2);
}

// ---- block5: bn finalize (8-shard sum) + gelu + partial max/sum ----
__global__ void k_apply5(const float* __restrict__ h5, const float* __restrict__ s1,
                         const float* __restrict__ s2, const float* __restrict__ g,
                         const float* __restrict__ b, float* __restrict__ pmax,
                         float* __restrict__ psum) {
    int o = blockIdx.x * 256 + threadIdx.x;
    int ch = blockIdx.y;
    int bb = blockIdx.z;
    float a1 = 0.f, a2 = 0.f;
    #pragma unroll
    for (int s = 0; s < 8; ++s) {
        a1 += s1[s * 1024 + o];
        a2 += s2[s * 1024 + o];
    }
    float mean = a1 * (1.0f / (BB * NN));
    float var = a2 * (1.0f / (BB * NN)) - mean * mean;
    float sc = g[o] * rsqrtf(var + 1e-5f);
    float sh = b[o] - mean * sc;
    int n0 = ch * (NN / 16);
    float mx = -INFINITY, sm = 0.f;
    for (int n = n0; n < n0 + NN / 16; ++n) {
        float v = gelu_erf(fmaf(sc, h5[((size_t)bb * NN + n) * 1024 + o], sh));
        mx = fmaxf(mx, v);
        sm += v;
    }
    pmax[((size_t)ch * BB + bb) * 1024 + o] = mx;
    psum[((size_t)ch * BB + bb) * 1024 + o] = sm;
}

__global__ void k_zfin(const float* __restrict__ pmax, const float* __restrict__ psum,
                       float* __restrict__ z) {
    int o = blockIdx.x * 256 + threadIdx.x;
    int bb = blockIdx.y;
    float mx = -INFINITY, sm = 0.f;
    for (int ch = 0; ch < 16; ++ch) {
        mx = fmaxf(mx, pmax[((size_t)ch * BB + bb) * 1024 + o]);
        sm += psum[((size_t)ch * BB + bb) * 1024 + o];
    }
    z[(size_t)bb * 2048 + o] = mx;
    z[(size_t)bb * 2048 + 1024 + o] = sm * (1.0f / NN);
}

// ---- FC gemv, optional fused batch-BN + leaky_relu ----
template <int DOBN>
__global__ void k_fc(const float* __restrict__ Z, int Kc, const float* __restrict__ W,
                     const float* __restrict__ bias, const float* __restrict__ g,
                     const float* __restrict__ b, float* __restrict__ out, int Oc) {
    int o = blockIdx.x;
    int lane = threadIdx.x;
    float acc[BB];
    #pragma unroll
    for (int q = 0; q < BB; ++q) acc[q] = 0.f;
    const float* wrow = W + (size_t)o * Kc;
    for (int i = lane; i < Kc; i += 64) {
        float wv = wrow[i];
        #pragma unroll
        for (int q = 0; q < BB; ++q) acc[q] = fmaf(Z[(size_t)q * Kc + i], wv, acc[q]);
    }
    #pragma unroll
    for (int s = 32; s > 0; s >>= 1) {
        #pragma unroll
        for (int q = 0; q < BB; ++q) acc[q] += __shfl_xor(acc[q], s);
    }
    if (lane == 0) {
        float bv = bias ? bias[o] : 0.f;
        float v[BB];
        #pragma unroll
        for (int q = 0; q < BB; ++q) v[q] = acc[q] + bv;
        if (DOBN) {
            float m = 0.f;
            #pragma unroll
            for (int q = 0; q < BB; ++q) m += v[q];
            m *= (1.0f / BB);
            float var = 0.f;
            #pragma unroll
            for (int q = 0; q < BB; ++q) { float d = v[q] - m; var = fmaf(d, d, var); }
            var *= (1.0f / BB);
            float sc = g[o] * rsqrtf(var + 1e-5f);
            #pragma unroll
            for (int q = 0; q < BB; ++q) {
                float y = fmaf(v[q] - m, sc, b[o]);
                v[q] = (y >= 0.f) ? y : 0.2f * y;
            }
        }
        #pragma unroll
        for (int q = 0; q < BB; ++q) out[(size_t)q * Oc + o] = v[q];
    }
}

extern "C" void kernel_launch(void* const* d_in, const int* in_sizes, int n_in,
                              void* d_out, int out_size, void* d_ws, size_t ws_size,
                              hipStream_t stream) {
    (void)in_sizes; (void)n_in; (void)out_size; (void)ws_size;
    const float* x   = (const float*)d_in[0];
    const float* W1  = (const float*)d_in[2];
    const float* g1  = (const float*)d_in[3];
    const float* b1  = (const float*)d_in[4];
    const float* W2  = (const float*)d_in[5];
    const float* g2  = (const float*)d_in[6];
    const float* b2  = (const float*)d_in[7];
    const float* W3  = (const float*)d_in[8];
    const float* g3  = (const float*)d_in[9];
    const float* b3  = (const float*)d_in[10];
    const float* W4  = (const float*)d_in[11];
    const float* g4  = (const float*)d_in[12];
    const float* b4  = (const float*)d_in[13];
    const float* W5  = (const float*)d_in[14];
    const float* g5  = (const float*)d_in[15];
    const float* b5  = (const float*)d_in[16];
    const float* Wl1 = (const float*)d_in[17];
    const float* g6  = (const float*)d_in[18];
    const float* b6  = (const float*)d_in[19];
    const float* Wl2 = (const float*)d_in[20];
    const float* bl2 = (const float*)d_in[21];
    const float* g7  = (const float*)d_in[22];
    const float* b7  = (const float*)d_in[23];
    const float* Wl3 = (const float*)d_in[24];
    const float* bl3 = (const float*)d_in[25];

    char* p = (char*)d_ws;
    auto carve = [&](size_t nbytes) {
        char* q = p;
        p += (nbytes + 255) & ~(size_t)255;
        return (void*)q;
    };
    float* x0   = (float*)carve((size_t)BB * NN * 3 * 4);
    float* negd = (float*)carve((size_t)BB * NN * NN * 4);    // reused as hmin/hmax
    int*   idx  = (int*)carve((size_t)BB * NN * KNN * 4);
    float* uw   = (float*)carve((size_t)BB * NN * 1024 * 4);  // u|w rows; also h5
    u16*   xch  = (u16*)carve((size_t)BB * NN * 960 * 2);
    u16*   xcl  = (u16*)carve((size_t)BB * NN * 960 * 2);
    u16*   wh   = (u16*)carve((size_t)SEGT * 2);
    u16*   wl   = (u16*)carve((size_t)SEGT * 2);
    float* sz   = (float*)carve((size_t)ZERO_TOTAL * 4);
    float* sqb  = sz + STATS_TOTAL;
    float* scale= (float*)carve(1024 * 4);
    float* shiftv = (float*)carve(1024 * 4);
    float* pmax = (float*)carve((size_t)16 * BB * 1024 * 4);
    float* psum = (float*)carve((size_t)16 * BB * 1024 * 4);
    float* z    = (float*)carve((size_t)BB * 2048 * 4);
    float* z1   = (float*)carve((size_t)BB * 512 * 4);
    float* z2   = (float*)carve((size_t)BB * 256 * 4);
    float* hmin = negd;
    float* hmax = negd + (size_t)BB * NN * 512;

    k_transpose<<<dim3(32), dim3(256), 0, stream>>>(x, x0, sz);
    k_prep_w<<<dim3(SEGT / 256), dim3(256), 0, stream>>>(W2, W3, W4, W5, wh, wl);

    const float* gs[4] = {g1, g2, g3, g4};
    const float* bs[4] = {b1, b2, b3, b4};
    int Cs[4] = {3, 64, 128, 256};
    int Os[4] = {64, 128, 256, 512};
    int coloff[4] = {0, 64, 192, 448};
    int ioff[4]   = {0, 0, 64, 192};
    int woff[4] = {0, 0, SEG2, SEG3};
    int ctcs[4] = {16, 32, 64, 64};
    int gys[4]  = {1, 1, 1, 2};
    int Rs[4]   = {16, 8, 8, 8};
    int shifts[4] = {4, 5, 6, 7};
    float cnt_inv = 1.0f / ((float)BB * NN * KNN);

    for (int blk = 0; blk < 4; ++blk) {
        int C = Cs[blk], O = Os[blk];
        if (blk == 0) {
            k_negd<<<dim3(8, 8, BB), dim3(256), 0, stream>>>(x0, 3, 3, negd);
            k_topk<<<dim3(BB * NN / 8), dim3(256), 0, stream>>>(negd, idx);
            k_uw1<<<dim3(BB * NN * 128 / 256), dim3(256), 0, stream>>>(x0, W1, uw);
        } else {
            k_mfma_comb<<<dim3(64, 8 + 2 * O / 128), dim3(256), 0, stream>>>(
                xch + ioff[blk], xcl + ioff[blk],
                wh + woff[blk], wl + woff[blk],
                sqb + (blk - 1) * 8192, negd, uw, C, 2 * O);
            k_topk<<<dim3(BB * NN / 8), dim3(256), 0, stream>>>(negd, idx);
        }
        float* s1 = sz + blk * STATS_BLK;
        float* s2 = s1 + 16 * O;
        k_gather4<<<dim3(8 * (NN / Rs[blk]), gys[blk]), dim3(256), 0, stream>>>(
            uw, idx, O, ctcs[blk], Rs[blk], hmin, hmax, s1, s2);
        k_bnfin<<<dim3((O + 255) / 256), dim3(256), 0, stream>>>(
            s1, s2, gs[blk], bs[blk], cnt_inv, O, scale, shiftv);
        k_apply<<<dim3(BB * NN * (O / 4) / 256), dim3(256), 0, stream>>>(
            hmin, hmax, scale, shiftv, O, shifts[blk],
            xch, xcl, coloff[blk], (blk < 3) ? (sqb + blk * 8192) : (float*)nullptr);
    }

    // ---- block 5 ----
    k_mfma16<<<dim3(16, 64), dim3(256), 0, stream>>>(
        xch, xcl, 960, wh + SEG4, wl + SEG4, 960, uw, 1024, 960);
    float* s15 = sz + 4 * STATS_BLK;
    float* s25 = s15 + 8 * 1024;
    k_colstats<<<dim3(4, BB * NN / 64), dim3(256), 0, stream>>>(uw, s15, s25);
    k_apply5<<<dim3(4, 16, BB), dim3(256), 0, stream>>>(uw, s15, s25, g5, b5, pmax, psum);
    k_zfin<<<dim3(4, BB), dim3(256), 0, stream>>>(pmax, psum, z);

    // ---- FC head ----
    k_fc<1><<<dim3(512), dim3(64), 0, stream>>>(z, 2048, Wl1, (const float*)nullptr, g6, b6, z1, 512);
    k_fc<1><<<dim3(256), dim3(64), 0, stream>>>(z1, 512, Wl2, bl2, g7, b7, z2, 256);
    k_fc<0><<<dim3(40), dim3(64), 0, stream>>>(z2, 256, Wl3, bl3, (const float*)nullptr,
                                               (const float*)nullptr, (float*)d_out, 40);
}

// Round 19
// 617.805 us; speedup vs baseline: 1.0299x; 1.0299x over previous
//
#include <hip/hip_runtime.h>
#include <math.h>

#define BB 8
#define NN 1024
#define KNN 20

typedef unsigned short u16;
typedef __bf16 bf16x8 __attribute__((ext_vector_type(8)));
typedef float floatx4 __attribute__((ext_vector_type(4)));

__device__ __forceinline__ float gelu_erf(float x) {
    return 0.5f * x * (1.0f + erff(x * 0.70710678118654752440f));
}

__device__ __forceinline__ u16 f2bf(float f) {
    unsigned int u = __float_as_uint(f);
    unsigned int r = (u + 0x7fffu + ((u >> 16) & 1u)) >> 16;
    return (u16)r;
}
__device__ __forceinline__ float bf2f(u16 h) {
    return __uint_as_float(((unsigned int)h) << 16);
}

// stats layout: 4 edge blocks x (s1[16][O] | s2[16][O]) + blk5 (s1[8][1024] | s2[8][1024])
#define STATS_BLK 32768
#define STATS_TOTAL (4 * STATS_BLK + 16384)
#define ZERO_TOTAL (STATS_TOTAL + 3 * 8192)

// ---- transpose x (B,C,N) -> x0 (B,N,3); zero stat + sq regions ----
__global__ void k_transpose(const float* __restrict__ x, float* __restrict__ x0,
                            float* __restrict__ sz) {
    int t = blockIdx.x * 256 + threadIdx.x;
    for (int i = t; i < ZERO_TOTAL; i += BB * NN) sz[i] = 0.f;
    if (t >= BB * NN) return;
    int b = t / NN, n = t % NN;
    #pragma unroll
    for (int c = 0; c < 3; ++c) x0[(size_t)t * 3 + c] = x[((size_t)b * 3 + c) * NN + n];
}

// ---- one-time weight prep ----
#define SEG2 16384
#define SEG3 81920
#define SEG4 344064
#define SEGT 1327104
__global__ void k_prep_w(const float* __restrict__ W2, const float* __restrict__ W3,
                         const float* __restrict__ W4, const float* __restrict__ W5,
                         u16* __restrict__ wh, u16* __restrict__ wl) {
    int t = blockIdx.x * 256 + threadIdx.x;
    if (t >= SEGT) return;
    float v;
    if (t < SEG2) {
        int row = t >> 6, c = t & 63;
        v = (row < 128) ? W2[row * 128 + c]
                        : W2[(row - 128) * 128 + 64 + c] - W2[(row - 128) * 128 + c];
    } else if (t < SEG3) {
        int i = t - SEG2;
        int row = i >> 7, c = i & 127;
        v = (row < 256) ? W3[row * 256 + c]
                        : W3[(row - 256) * 256 + 128 + c] - W3[(row - 256) * 256 + c];
    } else if (t < SEG4) {
        int i = t - SEG3;
        int row = i >> 8, c = i & 255;
        v = (row < 512) ? W4[row * 512 + c]
                        : W4[(row - 512) * 512 + 256 + c] - W4[(row - 512) * 512 + c];
    } else {
        int i = t - SEG4;
        int row = i / 960, c = i % 960;
        v = W5[row * 960 + c];
    }
    u16 h = f2bf(v);
    wh[t] = h;
    wl[t] = f2bf(v - bf2f(h));
}

// ---- fp32 negd for blk1 (C=3): exact ----
__global__ void k_negd(const float* __restrict__ X, int SA, int Kc, float* __restrict__ out) {
    int bz = blockIdx.z;
    const float* Xb = X + (size_t)bz * NN * SA;
    float* Cout = out + (size_t)bz * NN * NN;
    int m0 = blockIdx.y * 128, n0 = blockIdx.x * 128;
    __shared__ float As[16][132];
    __shared__ float Bs[16][132];
    __shared__ float sqA[128];
    __shared__ float sqB[128];
    int t = threadIdx.x;
    int tx = t & 15, ty = t >> 4;
    int r = t >> 1, kb = (t & 1) * 8;
    float acc[2][2][4][4] = {};
    float sqa = 0.f, sqb = 0.f;
    for (int k0 = 0; k0 < Kc; k0 += 16) {
        const float* srcA = Xb + (size_t)(m0 + r) * SA + k0 + kb;
        const float* srcB = Xb + (size_t)(n0 + r) * SA + k0 + kb;
        #pragma unroll
        for (int i = 0; i < 8; ++i) {
            float va = (k0 + kb + i < Kc) ? srcA[i] : 0.f;
            float vb = (k0 + kb + i < Kc) ? srcB[i] : 0.f;
            As[kb + i][r] = va;
            Bs[kb + i][r] = vb;
            sqa = fmaf(va, va, sqa);
            sqb = fmaf(vb, vb, sqb);
        }
        __syncthreads();
        #pragma unroll
        for (int kk = 0; kk < 16; ++kk) {
            float4 a0 = *(const float4*)&As[kk][ty * 4];
            float4 a1 = *(const float4*)&As[kk][64 + ty * 4];
            float4 b0 = *(const float4*)&Bs[kk][tx * 4];
            float4 b1 = *(const float4*)&Bs[kk][64 + tx * 4];
            float av[2][4] = {{a0.x, a0.y, a0.z, a0.w}, {a1.x, a1.y, a1.z, a1.w}};
            float bv[2][4] = {{b0.x, b0.y, b0.z, b0.w}, {b1.x, b1.y, b1.z, b1.w}};
            #pragma unroll
            for (int hm = 0; hm < 2; ++hm)
                #pragma unroll
                for (int hn = 0; hn < 2; ++hn)
                    #pragma unroll
                    for (int i = 0; i < 4; ++i)
                        #pragma unroll
                        for (int j = 0; j < 4; ++j)
                            acc[hm][hn][i][j] = fmaf(av[hm][i], bv[hn][j], acc[hm][hn][i][j]);
        }
        __syncthreads();
    }
    sqa += __shfl_xor(sqa, 1);
    sqb += __shfl_xor(sqb, 1);
    if ((t & 1) == 0) { sqA[r] = sqa; sqB[r] = sqb; }
    __syncthreads();
    #pragma unroll
    for (int hm = 0; hm < 2; ++hm)
        #pragma unroll
        for (int i = 0; i < 4; ++i) {
            int lrow = hm * 64 + ty * 4 + i;
            float sm = sqA[lrow];
            float* crow = Cout + (size_t)(m0 + lrow) * NN + n0;
            #pragma unroll
            for (int hn = 0; hn < 2; ++hn) {
                float4 sn = *(const float4*)&sqB[hn * 64 + tx * 4];
                float4 v;
                v.x = 2.f * acc[hm][hn][i][0] - sm - sn.x;
                v.y = 2.f * acc[hm][hn][i][1] - sm - sn.y;
                v.z = 2.f * acc[hm][hn][i][2] - sm - sn.z;
                v.w = 2.f * acc[hm][hn][i][3] - sm - sn.w;
                *(float4*)&crow[hn * 64 + tx * 4] = v;
            }
        }
}

// ============ combined GRAM + uw split-bf16 MFMA (blk2-4), one launch ============
// Fragment-major LDS layout [q-octet][row][8].
__global__ __launch_bounds__(256) void k_mfma_comb(
    const u16* __restrict__ Ah, const u16* __restrict__ Al,
    const u16* __restrict__ Wh, const u16* __restrict__ Wl,
    const float* __restrict__ sqg,
    float* __restrict__ negdOut, float* __restrict__ uwOut,
    int K, int ldUw) {
    const int lda = 960;
    int bx = blockIdx.x, by = blockIdx.y;
    bool gram = (by < 8);
    int m0, n0, rowBase;
    const u16 *pBh, *pBl;
    size_t ldb;
    float* pC;
    if (gram) {
        int b = bx & 7;
        n0 = (bx >> 3) * 128;
        m0 = by * 128;
        rowBase = b * NN;
        pBh = Ah; pBl = Al; ldb = lda;
        pC = negdOut + (size_t)b * NN * NN;
    } else {
        m0 = bx * 128;
        n0 = (by - 8) * 128;
        rowBase = 0;
        pBh = Wh; pBl = Wl; ldb = K;
        pC = uwOut;
    }
    __shared__ u16 sAh[4 * 1024];
    __shared__ u16 sAl[4 * 1024];
    __shared__ u16 sBh[4 * 1024];
    __shared__ u16 sBl[4 * 1024];
    __shared__ float sqA[128];
    __shared__ float sqB[128];
    int t = threadIdx.x;
    int w = t >> 6, lane = t & 63;
    int wm = (w & 1) * 64, wn = (w >> 1) * 64;
    int q = lane >> 4, lm = lane & 15;
    int r = t >> 1, cb = (t & 1) * 16;
    int q0 = (t & 1) * 2;
    if (gram) {
        if (t < 128) sqA[t] = sqg[rowBase + m0 + t];
        else if (t < 256) sqB[t - 128] = sqg[rowBase + n0 + (t - 128)];
    }
    floatx4 acc[4][4];
    #pragma unroll
    for (int i = 0; i < 4; ++i)
        #pragma unroll
        for (int j = 0; j < 4; ++j) {
            floatx4 z = {0.f, 0.f, 0.f, 0.f};
            acc[i][j] = z;
        }
    for (int k0 = 0; k0 < K; k0 += 32) {
        {
            size_t oa = (size_t)(rowBase + m0 + r) * lda + k0 + cb;
            size_t ob = gram ? (size_t)(rowBase + n0 + r) * lda + k0 + cb
                             : (size_t)(n0 + r) * ldb + k0 + cb;
            float4 ah0 = *(const float4*)&Ah[oa];
            float4 ah1 = *(const float4*)&Ah[oa + 8];
            float4 al0 = *(const float4*)&Al[oa];
            float4 al1 = *(const float4*)&Al[oa + 8];
            float4 bh0 = *(const float4*)&pBh[ob];
            float4 bh1 = *(const float4*)&pBh[ob + 8];
            float4 bl0 = *(const float4*)&pBl[ob];
            float4 bl1 = *(const float4*)&pBl[ob + 8];
            *(float4*)&sAh[q0 * 1024 + r * 8] = ah0;
            *(float4*)&sAh[(q0 + 1) * 1024 + r * 8] = ah1;
            *(float4*)&sAl[q0 * 1024 + r * 8] = al0;
            *(float4*)&sAl[(q0 + 1) * 1024 + r * 8] = al1;
            *(float4*)&sBh[q0 * 1024 + r * 8] = bh0;
            *(float4*)&sBh[(q0 + 1) * 1024 + r * 8] = bh1;
            *(float4*)&sBl[q0 * 1024 + r * 8] = bl0;
            *(float4*)&sBl[(q0 + 1) * 1024 + r * 8] = bl1;
        }
        __syncthreads();
        bf16x8 ah[4], al[4], bh[4], bl[4];
        #pragma unroll
        for (int i = 0; i < 4; ++i) {
            ah[i] = *(const bf16x8*)&sAh[q * 1024 + (wm + i * 16 + lm) * 8];
            al[i] = *(const bf16x8*)&sAl[q * 1024 + (wm + i * 16 + lm) * 8];
        }
        #pragma unroll
        for (int j = 0; j < 4; ++j) {
            bh[j] = *(const bf16x8*)&sBh[q * 1024 + (wn + j * 16 + lm) * 8];
            bl[j] = *(const bf16x8*)&sBl[q * 1024 + (wn + j * 16 + lm) * 8];
        }
        #pragma unroll
        for (int i = 0; i < 4; ++i)
            #pragma unroll
            for (int j = 0; j < 4; ++j) {
                acc[i][j] = __builtin_amdgcn_mfma_f32_16x16x32_bf16(ah[i], bh[j], acc[i][j], 0, 0, 0);
                acc[i][j] = __builtin_amdgcn_mfma_f32_16x16x32_bf16(ah[i], bl[j], acc[i][j], 0, 0, 0);
                acc[i][j] = __builtin_amdgcn_mfma_f32_16x16x32_bf16(al[i], bh[j], acc[i][j], 0, 0, 0);
            }
        __syncthreads();
    }
    if (gram) {
        #pragma unroll
        for (int i = 0; i < 4; ++i)
            #pragma unroll
            for (int j = 0; j < 4; ++j) {
                int coll = wn + j * 16 + lm;
                float sn = sqB[coll];
                #pragma unroll
                for (int rr = 0; rr < 4; ++rr) {
                    int rowl = wm + i * 16 + q * 4 + rr;
                    pC[(size_t)(m0 + rowl) * NN + n0 + coll] =
                        2.f * acc[i][j][rr] - sqA[rowl] - sn;
                }
            }
    } else {
        #pragma unroll
        for (int i = 0; i < 4; ++i) {
            int rowb = m0 + wm + i * 16 + q * 4;
            #pragma unroll
            for (int j = 0; j < 4; ++j) {
                int col = n0 + wn + j * 16 + lm;
                #pragma unroll
                for (int rr = 0; rr < 4; ++rr)
                    pC[(size_t)(rowb + rr) * ldUw + col] = acc[i][j][rr];
            }
        }
    }
}

// ============ split-bf16 MFMA GEMM (block 5): 128x128, fragment-major (R14-proven) ============
__global__ __launch_bounds__(256) void k_mfma16(
    const u16* __restrict__ Ah, const u16* __restrict__ Al, int lda,
    const u16* __restrict__ Bh, const u16* __restrict__ Bl, int ldb,
    float* __restrict__ Cout, int ldc, int K) {
    int m0 = blockIdx.y * 128, n0 = blockIdx.x * 128;
    __shared__ u16 sAh[4 * 1024];
    __shared__ u16 sAl[4 * 1024];
    __shared__ u16 sBh[4 * 1024];
    __shared__ u16 sBl[4 * 1024];
    int t = threadIdx.x;
    int w = t >> 6, lane = t & 63;
    int wm = (w & 1) * 64, wn = (w >> 1) * 64;
    int q = lane >> 4, lm = lane & 15;
    int r = t >> 1, cb = (t & 1) * 16;
    int q0 = (t & 1) * 2;
    floatx4 acc[4][4];
    #pragma unroll
    for (int i = 0; i < 4; ++i)
        #pragma unroll
        for (int j = 0; j < 4; ++j) {
            floatx4 z = {0.f, 0.f, 0.f, 0.f};
            acc[i][j] = z;
        }
    for (int k0 = 0; k0 < K; k0 += 32) {
        {
            size_t oa = (size_t)(m0 + r) * lda + k0 + cb;
            size_t ob = (size_t)(n0 + r) * ldb + k0 + cb;
            float4 ah0 = *(const float4*)&Ah[oa];
            float4 ah1 = *(const float4*)&Ah[oa + 8];
            float4 al0 = *(const float4*)&Al[oa];
            float4 al1 = *(const float4*)&Al[oa + 8];
            float4 bh0 = *(const float4*)&Bh[ob];
            float4 bh1 = *(const float4*)&Bh[ob + 8];
            float4 bl0 = *(const float4*)&Bl[ob];
            float4 bl1 = *(const float4*)&Bl[ob + 8];
            *(float4*)&sAh[q0 * 1024 + r * 8] = ah0;
            *(float4*)&sAh[(q0 + 1) * 1024 + r * 8] = ah1;
            *(float4*)&sAl[q0 * 1024 + r * 8] = al0;
            *(float4*)&sAl[(q0 + 1) * 1024 + r * 8] = al1;
            *(float4*)&sBh[q0 * 1024 + r * 8] = bh0;
            *(float4*)&sBh[(q0 + 1) * 1024 + r * 8] = bh1;
            *(float4*)&sBl[q0 * 1024 + r * 8] = bl0;
            *(float4*)&sBl[(q0 + 1) * 1024 + r * 8] = bl1;
        }
        __syncthreads();
        bf16x8 ah[4], al[4], bh[4], bl[4];
        #pragma unroll
        for (int i = 0; i < 4; ++i) {
            ah[i] = *(const bf16x8*)&sAh[q * 1024 + (wm + i * 16 + lm) * 8];
            al[i] = *(const bf16x8*)&sAl[q * 1024 + (wm + i * 16 + lm) * 8];
        }
        #pragma unroll
        for (int j = 0; j < 4; ++j) {
            bh[j] = *(const bf16x8*)&sBh[q * 1024 + (wn + j * 16 + lm) * 8];
            bl[j] = *(const bf16x8*)&sBl[q * 1024 + (wn + j * 16 + lm) * 8];
        }
        #pragma unroll
        for (int i = 0; i < 4; ++i)
            #pragma unroll
            for (int j = 0; j < 4; ++j) {
                acc[i][j] = __builtin_amdgcn_mfma_f32_16x16x32_bf16(ah[i], bh[j], acc[i][j], 0, 0, 0);
                acc[i][j] = __builtin_amdgcn_mfma_f32_16x16x32_bf16(ah[i], bl[j], acc[i][j], 0, 0, 0);
                acc[i][j] = __builtin_amdgcn_mfma_f32_16x16x32_bf16(al[i], bh[j], acc[i][j], 0, 0, 0);
            }
        __syncthreads();
    }
    #pragma unroll
    for (int i = 0; i < 4; ++i) {
        int rowb = m0 + wm + i * 16 + q * 4;
        #pragma unroll
        for (int j = 0; j < 4; ++j) {
            int col = n0 + wn + j * 16 + lm;
            #pragma unroll
            for (int rr = 0; rr < 4; ++rr)
                Cout[(size_t)(rowb + rr) * ldc + col] = acc[i][j][rr];
        }
    }
}

// ---- top-k=20: 2 rows/wave, XCD-affine batch mapping (batch = bx&7, matches
// comb's gram writes so reads hit the owning XCD's L2), value-only butterfly ----
__global__ void k_topk(const float* __restrict__ negd, int* __restrict__ idxout) {
    int wv = threadIdx.x >> 6, lane = threadIdx.x & 63;
    int bx = blockIdx.x;
    int b = bx & 7, rg = bx >> 3;
    int rowA = b * NN + rg * 8 + wv * 2;
    int rowB = rowA + 1;
    const float* dA = negd + (size_t)rowA * NN;
    const float* dB = negd + (size_t)rowB * NN;
    float va[16], vb[16];
    #pragma unroll
    for (int j = 0; j < 16; ++j) {
        va[j] = dA[j * 64 + lane];
        vb[j] = dB[j * 64 + lane];
    }
    float lva = va[0], lvb = vb[0];
    int lca = lane, lcb = lane;
    #pragma unroll
    for (int j = 1; j < 16; ++j) {
        int c = j * 64 + lane;
        if (va[j] > lva) { lva = va[j]; lca = c; }
        if (vb[j] > lvb) { lvb = vb[j]; lcb = c; }
    }
    for (int it = 0; it < KNN; ++it) {
        float ta = lva, tb = lvb;
        #pragma unroll
        for (int s = 32; s >= 1; s >>= 1) {
            float oa = __shfl_xor(ta, s);
            float ob = __shfl_xor(tb, s);
            ta = fmaxf(ta, oa);
            tb = fmaxf(tb, ob);
        }
        unsigned long long ma = __ballot(lva == ta);
        unsigned long long mb = __ballot(lvb == tb);
        int wa = 0x7fffffff, wb = 0x7fffffff;
        while (ma) {
            int l = __ffsll((unsigned long long)ma) - 1;
            int c = __shfl(lca, l);
            wa = min(wa, c);
            ma &= ma - 1;
        }
        while (mb) {
            int l = __ffsll((unsigned long long)mb) - 1;
            int c = __shfl(lcb, l);
            wb = min(wb, c);
            mb &= mb - 1;
        }
        if (lane == 0) {
            idxout[(size_t)rowA * KNN + it] = wa;
            idxout[(size_t)rowB * KNN + it] = wb;
        }
        if ((wa & 63) == lane) {
            int jd = wa >> 6;
            #pragma unroll
            for (int j = 0; j < 16; ++j)
                if (j == jd) va[j] = -INFINITY;
            lva = -INFINITY; lca = 0x7fffffff;
            #pragma unroll
            for (int j = 0; j < 16; ++j) {
                int c = j * 64 + lane;
                if (va[j] > lva) { lva = va[j]; lca = c; }
            }
        }
        if ((wb & 63) == lane) {
            int jd = wb >> 6;
            #pragma unroll
            for (int j = 0; j < 16; ++j)
                if (j == jd) vb[j] = -INFINITY;
            lvb = -INFINITY; lcb = 0x7fffffff;
            #pragma unroll
            for (int j = 0; j < 16; ++j) {
                int c = j * 64 + lane;
                if (vb[j] > lvb) { lvb = vb[j]; lcb = c; }
            }
        }
    }
}

// ---- blk1 uw direct ----
__global__ void k_uw1(const float* __restrict__ x0, const float* __restrict__ W1,
                      float* __restrict__ uw) {
    int t = blockIdx.x * 256 + threadIdx.x;
    if (t >= BB * NN * 128) return;
    int r = t >> 7, o = t & 127;
    float xv0 = x0[(size_t)r * 3], xv1 = x0[(size_t)r * 3 + 1], xv2 = x0[(size_t)r * 3 + 2];
    float acc;
    if (o < 64) {
        const float* wr = W1 + (size_t)o * 6;
        acc = wr[0] * xv0 + wr[1] * xv1 + wr[2] * xv2;
    } else {
        const float* wr = W1 + (size_t)(o - 64) * 6;
        acc = (wr[3] - wr[0]) * xv0 + (wr[4] - wr[1]) * xv1 + (wr[5] - wr[2]) * xv2;
    }
    uw[(size_t)t] = acc;
}

// ---- gather v4: R rows/block, gy channel split, 16-sharded stat atomics ----
__global__ void k_gather4(const float* __restrict__ uw, const int* __restrict__ idx,
                          int O, int ctc, int R,
                          float* __restrict__ hmin, float* __restrict__ hmax,
                          float* __restrict__ s1, float* __restrict__ s2) {
    int t = threadIdx.x;
    int ct = t % ctc, rt = t / ctc;
    int rowsPer = (R * ctc) >> 8;
    int bx = blockIdx.x;
    int b = bx & 7, rg = bx >> 3;
    int row0 = b * NN + rg * R;
    int shard = bx & 15;
    int o4 = blockIdx.y * (ctc * 4) + ct * 4;
    __shared__ int sidx[16 * KNN];
    __shared__ float4 red1[256];
    __shared__ float4 red2[256];
    for (int i = t; i < R * KNN; i += 256) sidx[i] = idx[(size_t)row0 * KNN + i];
    __syncthreads();
    int twoO = 2 * O;
    const float* ubase = uw + (size_t)b * NN * twoO;
    float a1[4] = {0, 0, 0, 0}, a2[4] = {0, 0, 0, 0};
    for (int rr = rt * rowsPer; rr < (rt + 1) * rowsPer; ++rr) {
        int nrow = row0 + rr;
        float4 w4 = *(const float4*)(uw + (size_t)nrow * twoO + O + o4);
        float wv[4] = {w4.x, w4.y, w4.z, w4.w};
        float mn[4], mx[4];
        #pragma unroll
        for (int qq = 0; qq < 4; ++qq) { mn[qq] = INFINITY; mx[qq] = -INFINITY; }
        #pragma unroll 4
        for (int j = 0; j < KNN; ++j) {
            int m = sidx[rr * KNN + j];
            float4 u4 = *(const float4*)(ubase + (size_t)m * twoO + o4);
            float uv[4] = {u4.x, u4.y, u4.z, u4.w};
            #pragma unroll
            for (int qq = 0; qq < 4; ++qq) {
                float h = uv[qq] + wv[qq];
                mn[qq] = fminf(mn[qq], h);
                mx[qq] = fmaxf(mx[qq], h);
                a1[qq] += h;
                a2[qq] = fmaf(h, h, a2[qq]);
            }
        }
        *(float4*)&hmin[(size_t)nrow * O + o4] = make_float4(mn[0], mn[1], mn[2], mn[3]);
        *(float4*)&hmax[(size_t)nrow * O + o4] = make_float4(mx[0], mx[1], mx[2], mx[3]);
    }
    red1[t] = make_float4(a1[0], a1[1], a1[2], a1[3]);
    red2[t] = make_float4(a2[0], a2[1], a2[2], a2[3]);
    __syncthreads();
    if (rt == 0) {
        int rs = 256 / ctc;
        for (int rr = 1; rr < rs; ++rr) {
            float4 v1 = red1[ct + rr * ctc];
            float4 v2 = red2[ct + rr * ctc];
            a1[0] += v1.x; a1[1] += v1.y; a1[2] += v1.z; a1[3] += v1.w;
            a2[0] += v2.x; a2[1] += v2.y; a2[2] += v2.z; a2[3] += v2.w;
        }
        #pragma unroll
        for (int qq = 0; qq < 4; ++qq) {
            atomicAdd(&s1[shard * O + o4 + qq], a1[qq]);
            atomicAdd(&s2[shard * O + o4 + qq], a2[qq]);
        }
    }
}

// ---- BN finalize: reduce 16 shards -> scale/shift ----
__global__ void k_bnfin(const float* __restrict__ s1, const float* __restrict__ s2,
                        const float* __restrict__ g, const float* __restrict__ b,
                        float cnt_inv, int O, float* __restrict__ scale,
                        float* __restrict__ shift) {
    int o = blockIdx.x * 256 + threadIdx.x;
    if (o >= O) return;
    float a1 = 0.f, a2 = 0.f;
    #pragma unroll
    for (int s = 0; s < 16; ++s) {
        a1 += s1[s * O + o];
        a2 += s2[s * O + o];
    }
    float mean = a1 * cnt_inv;
    float var = a2 * cnt_inv - mean * mean;
    float sc = g[o] * rsqrtf(var + 1e-5f);
    scale[o] = sc;
    shift[o] = b[o] - mean * sc;
}

// ---- apply: BN + GELU + maxpool -> bf16 hi/lo planes; optional row-sq ----
__global__ void k_apply(const float* __restrict__ hmin, const float* __restrict__ hmax,
                        const float* __restrict__ scale, const float* __restrict__ shiftv,
                        int O, int shift,
                        u16* __restrict__ outh, u16* __restrict__ outl, int coloff,
                        float* __restrict__ sqout) {
    int gidx = blockIdx.x * 256 + threadIdx.x;
    int row = gidx >> shift;
    int o4 = (gidx & ((1 << shift) - 1)) * 4;
    ushort4 vh, vl;
    float sq = 0.f;
    float vals[4];
    #pragma unroll
    for (int qq = 0; qq < 4; ++qq) {
        int o = o4 + qq;
        float sc = scale[o], sh = shiftv[o];
        float va = gelu_erf(fmaf(sc, hmax[(size_t)row * O + o], sh));
        float vb = gelu_erf(fmaf(sc, hmin[(size_t)row * O + o], sh));
        vals[qq] = fmaxf(va, vb);
        sq = fmaf(vals[qq], vals[qq], sq);
    }
    vh.x = f2bf(vals[0]); vl.x = f2bf(vals[0] - bf2f(vh.x));
    vh.y = f2bf(vals[1]); vl.y = f2bf(vals[1] - bf2f(vh.y));
    vh.z = f2bf(vals[2]); vl.z = f2bf(vals[2] - bf2f(vh.z));
    vh.w = f2bf(vals[3]); vl.w = f2bf(vals[3] - bf2f(vh.w));
    *(ushort4*)&outh[(size_t)row * 960 + coloff + o4] = vh;
    *(ushort4*)&outl[(size_t)row * 960 + coloff + o4] = vl;
    if (sqout) {
        int gsz = 1 << shift;
        if (gsz > 64) gsz = 64;
        #pragma unroll
        for (int s = 1; s < 64; s <<= 1) {
            if (s < gsz) sq += __shfl_xor(sq, s);
        }
        if ((threadIdx.x & (gsz - 1)) == 0) atomicAdd(&sqout[row], sq);
    }
}

// ---- block5: per-column sum/sumsq, 8-sharded ----
__global__ void k_colstats(const float* __restrict__ A, float* __restrict__ s1,
                           float* __restrict__ s2) {
    int o = blockIdx.x * 256 + threadIdx.x;
    int r0 = blockIdx.y * 64;
    int shard = blockIdx.y & 7;
    float a1 = 0.f, a2 = 0.f;
    for (int r = 0; r < 64; ++r) {
        float v = A[(size_t)(r0 + r) * 1024 + o];
        a1 += v;
        a2 = fmaf(v, v, a2);
    }
    atomicAdd(&s1[shard * 1024 + o], a1);
    atomicAdd(&s2[shard * 1024 + o], a2);
}

// ---- block5: bn finalize (8-shard sum) + gelu + partial max/sum ----
__global__ void k_apply5(const float* __restrict__ h5, const float* __restrict__ s1,
                         const float* __restrict__ s2, const float* __restrict__ g,
                         const float* __restrict__ b, float* __restrict__ pmax,
                         float* __restrict__ psum) {
    int o = blockIdx.x * 256 + threadIdx.x;
    int ch = blockIdx.y;
    int bb = blockIdx.z;
    float a1 = 0.f, a2 = 0.f;
    #pragma unroll
    for (int s = 0; s < 8; ++s) {
        a1 += s1[s * 1024 + o];
        a2 += s2[s * 1024 + o];
    }
    float mean = a1 * (1.0f / (BB * NN));
    float var = a2 * (1.0f / (BB * NN)) - mean * mean;
    float sc = g[o] * rsqrtf(var + 1e-5f);
    float sh = b[o] - mean * sc;
    int n0 = ch * (NN / 16);
    float mx = -INFINITY, sm = 0.f;
    for (int n = n0; n < n0 + NN / 16; ++n) {
        float v = gelu_erf(fmaf(sc, h5[((size_t)bb * NN + n) * 1024 + o], sh));
        mx = fmaxf(mx, v);
        sm += v;
    }
    pmax[((size_t)ch * BB + bb) * 1024 + o] = mx;
    psum[((size_t)ch * BB + bb) * 1024 + o] = sm;
}

__global__ void k_zfin(const float* __restrict__ pmax, const float* __restrict__ psum,
                       float* __restrict__ z) {
    int o = blockIdx.x * 256 + threadIdx.x;
    int bb = blockIdx.y;
    float mx = -INFINITY, sm = 0.f;
    for (int ch = 0; ch < 16; ++ch) {
        mx = fmaxf(mx, pmax[((size_t)ch * BB + bb) * 1024 + o]);
        sm += psum[((size_t)ch * BB + bb) * 1024 + o];
    }
    z[(size_t)bb * 2048 + o] = mx;
    z[(size_t)bb * 2048 + 1024 + o] = sm * (1.0f / NN);
}

// ---- FC gemv, optional fused batch-BN + leaky_relu ----
template <int DOBN>
__global__ void k_fc(const float* __restrict__ Z, int Kc, const float* __restrict__ W,
                     const float* __restrict__ bias, const float* __restrict__ g,
                     const float* __restrict__ b, float* __restrict__ out, int Oc) {
    int o = blockIdx.x;
    int lane = threadIdx.x;
    float acc[BB];
    #pragma unroll
    for (int q = 0; q < BB; ++q) acc[q] = 0.f;
    const float* wrow = W + (size_t)o * Kc;
    for (int i = lane; i < Kc; i += 64) {
        float wv = wrow[i];
        #pragma unroll
        for (int q = 0; q < BB; ++q) acc[q] = fmaf(Z[(size_t)q * Kc + i], wv, acc[q]);
    }
    #pragma unroll
    for (int s = 32; s > 0; s >>= 1) {
        #pragma unroll
        for (int q = 0; q < BB; ++q) acc[q] += __shfl_xor(acc[q], s);
    }
    if (lane == 0) {
        float bv = bias ? bias[o] : 0.f;
        float v[BB];
        #pragma unroll
        for (int q = 0; q < BB; ++q) v[q] = acc[q] + bv;
        if (DOBN) {
            float m = 0.f;
            #pragma unroll
            for (int q = 0; q < BB; ++q) m += v[q];
            m *= (1.0f / BB);
            float var = 0.f;
            #pragma unroll
            for (int q = 0; q < BB; ++q) { float d = v[q] - m; var = fmaf(d, d, var); }
            var *= (1.0f / BB);
            float sc = g[o] * rsqrtf(var + 1e-5f);
            #pragma unroll
            for (int q = 0; q < BB; ++q) {
                float y = fmaf(v[q] - m, sc, b[o]);
                v[q] = (y >= 0.f) ? y : 0.2f * y;
            }
        }
        #pragma unroll
        for (int q = 0; q < BB; ++q) out[(size_t)q * Oc + o] = v[q];
    }
}

extern "C" void kernel_launch(void* const* d_in, const int* in_sizes, int n_in,
                              void* d_out, int out_size, void* d_ws, size_t ws_size,
                              hipStream_t stream) {
    (void)in_sizes; (void)n_in; (void)out_size; (void)ws_size;
    const float* x   = (const float*)d_in[0];
    const float* W1  = (const float*)d_in[2];
    const float* g1  = (const float*)d_in[3];
    const float* b1  = (const float*)d_in[4];
    const float* W2  = (const float*)d_in[5];
    const float* g2  = (const float*)d_in[6];
    const float* b2  = (const float*)d_in[7];
    const float* W3  = (const float*)d_in[8];
    const float* g3  = (const float*)d_in[9];
    const float* b3  = (const float*)d_in[10];
    const float* W4  = (const float*)d_in[11];
    const float* g4  = (const float*)d_in[12];
    const float* b4  = (const float*)d_in[13];
    const float* W5  = (const float*)d_in[14];
    const float* g5  = (const float*)d_in[15];
    const float* b5  = (const float*)d_in[16];
    const float* Wl1 = (const float*)d_in[17];
    const float* g6  = (const float*)d_in[18];
    const float* b6  = (const float*)d_in[19];
    const float* Wl2 = (const float*)d_in[20];
    const float* bl2 = (const float*)d_in[21];
    const float* g7  = (const float*)d_in[22];
    const float* b7  = (const float*)d_in[23];
    const float* Wl3 = (const float*)d_in[24];
    const float* bl3 = (const float*)d_in[25];

    char* p = (char*)d_ws;
    auto carve = [&](size_t nbytes) {
        char* q = p;
        p += (nbytes + 255) & ~(size_t)255;
        return (void*)q;
    };
    float* x0   = (float*)carve((size_t)BB * NN * 3 * 4);
    float* negd = (float*)carve((size_t)BB * NN * NN * 4);    // reused as hmin/hmax
    int*   idx  = (int*)carve((size_t)BB * NN * KNN * 4);
    float* uw   = (float*)carve((size_t)BB * NN * 1024 * 4);  // u|w rows; also h5
    u16*   xch  = (u16*)carve((size_t)BB * NN * 960 * 2);
    u16*   xcl  = (u16*)carve((size_t)BB * NN * 960 * 2);
    u16*   wh   = (u16*)carve((size_t)SEGT * 2);
    u16*   wl   = (u16*)carve((size_t)SEGT * 2);
    float* sz   = (float*)carve((size_t)ZERO_TOTAL * 4);
    float* sqb  = sz + STATS_TOTAL;
    float* scale= (float*)carve(1024 * 4);
    float* shiftv = (float*)carve(1024 * 4);
    float* pmax = (float*)carve((size_t)16 * BB * 1024 * 4);
    float* psum = (float*)carve((size_t)16 * BB * 1024 * 4);
    float* z    = (float*)carve((size_t)BB * 2048 * 4);
    float* z1   = (float*)carve((size_t)BB * 512 * 4);
    float* z2   = (float*)carve((size_t)BB * 256 * 4);
    float* hmin = negd;
    float* hmax = negd + (size_t)BB * NN * 512;

    k_transpose<<<dim3(32), dim3(256), 0, stream>>>(x, x0, sz);
    k_prep_w<<<dim3(SEGT / 256), dim3(256), 0, stream>>>(W2, W3, W4, W5, wh, wl);

    const float* gs[4] = {g1, g2, g3, g4};
    const float* bs[4] = {b1, b2, b3, b4};
    int Cs[4] = {3, 64, 128, 256};
    int Os[4] = {64, 128, 256, 512};
    int coloff[4] = {0, 64, 192, 448};
    int ioff[4]   = {0, 0, 64, 192};
    int woff[4] = {0, 0, SEG2, SEG3};
    int ctcs[4] = {16, 32, 64, 64};
    int gys[4]  = {1, 1, 1, 2};
    int Rs[4]   = {16, 8, 8, 8};
    int shifts[4] = {4, 5, 6, 7};
    float cnt_inv = 1.0f / ((float)BB * NN * KNN);

    for (int blk = 0; blk < 4; ++blk) {
        int C = Cs[blk], O = Os[blk];
        if (blk == 0) {
            k_negd<<<dim3(8, 8, BB), dim3(256), 0, stream>>>(x0, 3, 3, negd);
            k_topk<<<dim3(BB * NN / 8), dim3(256), 0, stream>>>(negd, idx);
            k_uw1<<<dim3(BB * NN * 128 / 256), dim3(256), 0, stream>>>(x0, W1, uw);
        } else {
            k_mfma_comb<<<dim3(64, 8 + 2 * O / 128), dim3(256), 0, stream>>>(
                xch + ioff[blk], xcl + ioff[blk],
                wh + woff[blk], wl + woff[blk],
                sqb + (blk - 1) * 8192, negd, uw, C, 2 * O);
            k_topk<<<dim3(BB * NN / 8), dim3(256), 0, stream>>>(negd, idx);
        }
        float* s1 = sz + blk * STATS_BLK;
        float* s2 = s1 + 16 * O;
        k_gather4<<<dim3(8 * (NN / Rs[blk]), gys[blk]), dim3(256), 0, stream>>>(
            uw, idx, O, ctcs[blk], Rs[blk], hmin, hmax, s1, s2);
        k_bnfin<<<dim3((O + 255) / 256), dim3(256), 0, stream>>>(
            s1, s2, gs[blk], bs[blk], cnt_inv, O, scale, shiftv);
        k_apply<<<dim3(BB * NN * (O / 4) / 256), dim3(256), 0, stream>>>(
            hmin, hmax, scale, shiftv, O, shifts[blk],
            xch, xcl, coloff[blk], (blk < 3) ? (sqb + blk * 8192) : (float*)nullptr);
    }

    // ---- block 5 ----
    k_mfma16<<<dim3(8, 64), dim3(256), 0, stream>>>(
        xch, xcl, 960, wh + SEG4, wl + SEG4, 960, uw, 1024, 960);
    float* s15 = sz + 4 * STATS_BLK;
    float* s25 = s15 + 8 * 1024;
    k_colstats<<<dim3(4, BB * NN / 64), dim3(256), 0, stream>>>(uw, s15, s25);
    k_apply5<<<dim3(4, 16, BB), dim3(256), 0, stream>>>(uw, s15, s25, g5, b5, pmax, psum);
    k_zfin<<<dim3(4, BB), dim3(256), 0, stream>>>(pmax, psum, z);

    // ---- FC head ----
    k_fc<1><<<dim3(512), dim3(64), 0, stream>>>(z, 2048, Wl1, (const float*)nullptr, g6, b6, z1, 512);
    k_fc<1><<<dim3(256), dim3(64), 0, stream>>>(z1, 512, Wl2, bl2, g7, b7, z2, 256);
    k_fc<0><<<dim3(40), dim3(64), 0, stream>>>(z2, 256, Wl3, bl3, (const float*)nullptr,
                                               (const float*)nullptr, (float*)d_out, 40);
}